// Round 5
// baseline (81.818 us; speedup 1.0000x reference)
//
#include <hip/hip_runtime.h>
#include <hip/hip_bf16.h>

// Problem constants (match reference)
#define B 8
#define S 512
#define D 768
#define N 512
#define MAX_W 16
#define BLOCK 192
#define ROW_F 196   // padded LDS row stride in floats (192+4); 784 B keeps 16B alignment

// ---------------------------------------------------------------------------
// Fully fused: one block per span (192 threads; thread t owns float4 chunk t
// of the D=768 row).
//  1. Gather rows start..start+width into registers v[i] (coalesced float4),
//     computing partial dots p[i] = v[i] . att_w_chunk on the fly.
//  2. LDS transpose-reduce the 16 partial-dot columns -> 16 span logits.
//     (att_b cancels: softmax is shift-invariant over the valid entries.)
//  3. Uniform 16-wide softmax (redundant per thread, no divergence).
//  4. Weighted sum straight from the registers v[i] -> out. No reload.
// XCD swizzle: bid -> span (bid%8)*512 + bid/8 so XCD x touches only batch
// x's 1.57 MB seq slice (fits private 4 MB L2). Bijective (4096 % 8 == 0).
// ---------------------------------------------------------------------------
__global__ __launch_bounds__(BLOCK) void fused_span_kernel(
    const float* __restrict__ seq,
    const int2*  __restrict__ spans,
    const float* __restrict__ att_w,
    float* __restrict__ out)
{
    __shared__ __align__(16) float lds1[MAX_W][ROW_F];
    __shared__ float lds2[MAX_W][12];
    __shared__ float lds3[MAX_W];

    const int bid  = blockIdx.x;
    const int span = (bid & 7) * (B * N / 8) + (bid >> 3);
    const int b    = span >> 9;                 // N = 512
    const int tid  = threadIdx.x;

    const int2 se   = spans[span];
    const int start = se.x;
    const int width = se.y - se.x;              // valid count - 1, in [0, 15]

    const float4 wv = ((const float4*)att_w)[tid];   // 3 KB, L2-hot
    const float4* seqb = (const float4*)(seq + ((size_t)b * S + start) * D);

    // --- 1. gather + partial dots (all loads independent -> full MLP) ---
    float4 v[MAX_W];
    float  p[MAX_W];
#pragma unroll
    for (int i = 0; i < MAX_W; ++i) {
        if (i <= width) {                        // block-uniform branch
            float4 t = seqb[i * (D / 4) + tid];
            v[i] = t;
            p[i] = t.x * wv.x + t.y * wv.y + t.z * wv.z + t.w * wv.w;
        } else {
            v[i] = make_float4(0.f, 0.f, 0.f, 0.f);
            p[i] = 0.f;
        }
    }

    // --- 2. block-reduce 16 partial dots: LDS transpose ---
#pragma unroll
    for (int i = 0; i < MAX_W; ++i) lds1[i][tid] = p[i];  // coalesced, conflict-free
    __syncthreads();

    const int r = tid / 12;                      // 0..15 (row)
    const int j = tid - r * 12;                  // 0..11
    const float4* row4 = (const float4*)(&lds1[r][0]);
    float s = 0.f;
#pragma unroll
    for (int k = 0; k < 4; ++k) {                // 16 floats per thread
        float4 t = row4[j * 4 + k];
        s += (t.x + t.y) + (t.z + t.w);
    }
    lds2[r][j] = s;
    __syncthreads();

    if (tid < MAX_W) {                           // 16 threads finish 12-way sums
        float t = 0.f;
#pragma unroll
        for (int q = 0; q < 12; ++q) t += lds2[tid][q];   // worst 2-way banks: free
        lds3[tid] = t;
    }
    __syncthreads();

    // --- 3. uniform softmax over valid entries ---
    float wgt[MAX_W];
    float m = -1e30f;
#pragma unroll
    for (int i = 0; i < MAX_W; ++i) {
        wgt[i] = lds3[i];                        // broadcast reads, free
        if (i <= width) m = fmaxf(m, wgt[i]);
    }
    float sum = 0.f;
#pragma unroll
    for (int i = 0; i < MAX_W; ++i) {
        float e = (i <= width) ? __expf(wgt[i] - m) : 0.f;
        wgt[i] = e;
        sum += e;
    }
    const float inv = 1.f / sum;   // ref's +1e-13 is ~1e-13 relative: negligible

    // --- 4. weighted sum from registers ---
    float4 acc = make_float4(0.f, 0.f, 0.f, 0.f);
#pragma unroll
    for (int i = 0; i < MAX_W; ++i) {
        if (i <= width) {
            const float w = wgt[i];
            acc.x += w * v[i].x;
            acc.y += w * v[i].y;
            acc.z += w * v[i].z;
            acc.w += w * v[i].w;
        }
    }
    acc.x *= inv; acc.y *= inv; acc.z *= inv; acc.w *= inv;

    ((float4*)(out + (size_t)span * D))[tid] = acc;
}

extern "C" void kernel_launch(void* const* d_in, const int* in_sizes, int n_in,
                              void* d_out, int out_size, void* d_ws, size_t ws_size,
                              hipStream_t stream) {
    const float* seq   = (const float*)d_in[0];   // (B,S,D) fp32
    const int2*  spans = (const int2*)d_in[1];    // (B,N,2) int32
    const float* att_w = (const float*)d_in[2];   // (D,)
    // d_in[3] (att_b) cancels under softmax renormalization — unused.
    float* out = (float*)d_out;                   // (B,N,D) fp32

    fused_span_kernel<<<B * N, BLOCK, 0, stream>>>(seq, spans, att_w, out);
}

// Round 6
// 81.192 us; speedup vs baseline: 1.0077x; 1.0077x over previous
//
#include <hip/hip_runtime.h>
#include <hip/hip_bf16.h>

// Problem constants (match reference)
#define B 8
#define S 512
#define D 768
#define N 512
#define MAX_W 16
#define BLOCK 192
#define ROW_F 196   // padded LDS row stride in floats (192+4); 784 B keeps 16B alignment

// ---------------------------------------------------------------------------
// Fused, LOW-VGPR variant: one block per span (192 threads; thread t owns
// float4 chunk t of the D=768 row).
//  Pass A: stream rows start..start+width (coalesced float4), computing ONLY
//          partial dots p[i] = row_chunk . att_w_chunk. Rows NOT retained
//          (v[16] cost 64 VGPRs and halved occupancy in the previous round).
//  LDS transpose-reduce -> 16 span logits (att_b cancels under softmax).
//  Uniform 16-wide softmax (redundant per thread, block-uniform branches).
//  Pass B: RELOAD rows (L2-hot: batch slice is 1.57 MB vs 4 MB XCD L2) and
//          accumulate the weighted sum -> out.
// __launch_bounds__(192, 6): >=6 waves/EU => ~24 waves/CU to hide gather
// latency (the gather is latency-bound, not BW-bound).
// XCD swizzle: bid -> span (bid%8)*512 + bid/8 so XCD x touches only batch
// x's seq slice. Bijective (4096 % 8 == 0).
// ---------------------------------------------------------------------------
__global__ __launch_bounds__(BLOCK, 6) void fused_span_kernel(
    const float* __restrict__ seq,
    const int2*  __restrict__ spans,
    const float* __restrict__ att_w,
    float* __restrict__ out)
{
    __shared__ __align__(16) float lds1[MAX_W][ROW_F];
    __shared__ float lds2[MAX_W][12];
    __shared__ float lds3[MAX_W];

    const int bid  = blockIdx.x;
    const int span = (bid & 7) * (B * N / 8) + (bid >> 3);
    const int b    = span >> 9;                 // N = 512
    const int tid  = threadIdx.x;

    const int2 se   = spans[span];
    const int start = se.x;
    const int width = se.y - se.x;              // valid count - 1, in [0, 15]

    const float4 wv = ((const float4*)att_w)[tid];   // 3 KB, L2-hot
    const float4* seqb = (const float4*)(seq + ((size_t)b * S + start) * D);

    // --- Pass A: partial dots only (independent loads -> full MLP) ---
    float p[MAX_W];
#pragma unroll
    for (int i = 0; i < MAX_W; ++i) {
        if (i <= width) {                        // block-uniform branch
            float4 t = seqb[i * (D / 4) + tid];
            p[i] = t.x * wv.x + t.y * wv.y + t.z * wv.z + t.w * wv.w;
        } else {
            p[i] = 0.f;
        }
    }

    // --- block-reduce 16 partial dots: LDS transpose ---
#pragma unroll
    for (int i = 0; i < MAX_W; ++i) lds1[i][tid] = p[i];  // coalesced, conflict-free
    __syncthreads();

    const int r = tid / 12;                      // 0..15 (row)
    const int j = tid - r * 12;                  // 0..11
    const float4* row4 = (const float4*)(&lds1[r][0]);
    float s = 0.f;
#pragma unroll
    for (int k = 0; k < 4; ++k) {                // 16 floats per thread
        float4 t = row4[j * 4 + k];
        s += (t.x + t.y) + (t.z + t.w);
    }
    lds2[r][j] = s;
    __syncthreads();

    if (tid < MAX_W) {                           // 16 threads finish 12-way sums
        float t = 0.f;
#pragma unroll
        for (int q = 0; q < 12; ++q) t += lds2[tid][q];   // worst 2-way banks: free
        lds3[tid] = t;
    }
    __syncthreads();

    // --- uniform softmax over valid entries (reuses p[] as weights) ---
    float m = -1e30f;
#pragma unroll
    for (int i = 0; i < MAX_W; ++i) {
        p[i] = lds3[i];                          // broadcast reads, free
        if (i <= width) m = fmaxf(m, p[i]);
    }
    float sum = 0.f;
#pragma unroll
    for (int i = 0; i < MAX_W; ++i) {
        float e = (i <= width) ? __expf(p[i] - m) : 0.f;
        p[i] = e;
        sum += e;
    }
    const float inv = 1.f / sum;   // ref's +1e-13 is ~1e-13 relative: negligible

    // --- Pass B: reload rows (L2-hot) and accumulate weighted sum ---
    float4 acc = make_float4(0.f, 0.f, 0.f, 0.f);
#pragma unroll
    for (int i = 0; i < MAX_W; ++i) {
        if (i <= width) {                        // block-uniform branch
            float4 v = seqb[i * (D / 4) + tid];
            const float w = p[i];
            acc.x += w * v.x;
            acc.y += w * v.y;
            acc.z += w * v.z;
            acc.w += w * v.w;
        }
    }
    acc.x *= inv; acc.y *= inv; acc.z *= inv; acc.w *= inv;

    ((float4*)(out + (size_t)span * D))[tid] = acc;
}

extern "C" void kernel_launch(void* const* d_in, const int* in_sizes, int n_in,
                              void* d_out, int out_size, void* d_ws, size_t ws_size,
                              hipStream_t stream) {
    const float* seq   = (const float*)d_in[0];   // (B,S,D) fp32
    const int2*  spans = (const int2*)d_in[1];    // (B,N,2) int32
    const float* att_w = (const float*)d_in[2];   // (D,)
    // d_in[3] (att_b) cancels under softmax renormalization — unused.
    float* out = (float*)d_out;                   // (B,N,D) fp32

    fused_span_kernel<<<B * N, BLOCK, 0, stream>>>(seq, spans, att_w, out);
}